// Round 13
// baseline (560.137 us; speedup 1.0000x reference)
//
#include <hip/hip_runtime.h>
#include <hip/hip_bf16.h>
#include <stdint.h>

#define NE 25690112ull   // 32*64*112*112
#define PP 12544         // 112*112
#define SS 112
#define EPSV 1e-5f
#define BSTR 802816      // 784*1024, u16 elements per b in tiled K layout

typedef __attribute__((ext_vector_type(8))) short short8v;
typedef __attribute__((ext_vector_type(4))) float float4v;

__device__ __forceinline__ unsigned short f2bf(float x){
  union { __hip_bfloat16 h; unsigned short u; } cv;
  cv.h = __float2bfloat16(x);
  return cv.u;
}
__device__ __forceinline__ ushort4 f2bf4(float a, float b, float c, float d){
  union { __hip_bfloat162 h2[2]; ushort4 u; } cv;
  cv.h2[0] = __float22bfloat162_rn(make_float2(a, b));
  cv.h2[1] = __float22bfloat162_rn(make_float2(c, d));
  return cv.u;
}
__device__ __forceinline__ float bf2f(unsigned short u){ return __uint_as_float(((uint32_t)u) << 16); }

// ---------------- K1: conv1x1 via MFMA; q linear, K TILED direct stores ----------------
// Tiled layout for kF/kL: element (b, c, p) at (b*784 + p/16)*1024 + c*16 + (p%16).
// K's MFMA D-frags store 512B-contiguous directly (no LDS staging, no syncs).
__global__ __launch_bounds__(256) void k1_conv(
    const float* __restrict__ rgb, const float* __restrict__ fre,
    const float* __restrict__ wq_fad, const float* __restrict__ bq_fad,
    const float* __restrict__ wk_fad, const float* __restrict__ bk_fad,
    const float* __restrict__ wq_lfs, const float* __restrict__ bq_lfs,
    const float* __restrict__ wk_lfs, const float* __restrict__ bk_lfs,
    unsigned short* __restrict__ qF, unsigned short* __restrict__ kFt,
    unsigned short* __restrict__ qL, unsigned short* __restrict__ kLt)
{
  const int bx = blockIdx.x, b = blockIdx.y, z = blockIdx.z;
  const float* X  = z ? fre : rgb;
  const float* Wq = z ? wq_lfs : wq_fad;
  const float* Bq = z ? bq_lfs : bq_fad;
  const float* Wk = z ? wk_lfs : wk_fad;
  const float* Bk = z ? bk_lfs : bk_fad;
  unsigned short* Oq = z ? qL : qF;
  unsigned short* Ok = z ? kLt : kFt;

  __shared__ __align__(16) unsigned short xs[256 * 64];   // 32 KB

  const int tid = threadIdx.x, lane = tid & 63, w = tid >> 6;
  const int lc = lane & 15, l4 = lane >> 4;

  // ---- Phase A: stage 256p x 64c, 4x4 micro-transpose into [p][c] swizzled ----
  const int p0 = bx*256;
  const size_t xbase = (size_t)b * 64 * PP;
  const int c0 = (tid & 15) * 4;
  const int pq = (tid >> 4) * 4;
  #pragma unroll
  for (int itp = 0; itp < 4; ++itp){
    const int p = itp*64 + pq;
    float4 xr[4];
    #pragma unroll
    for (int k = 0; k < 4; ++k)
      xr[k] = *(const float4*)(X + xbase + (size_t)(c0+k)*PP + p0 + p);
    const float* v0 = &xr[0].x;
    const float* v1 = &xr[1].x;
    const float* v2 = &xr[2].x;
    const float* v3 = &xr[3].x;
    #pragma unroll
    for (int j = 0; j < 4; ++j){
      ushort4 t = f2bf4(v0[j], v1[j], v2[j], v3[j]);
      uint32_t byteS = (uint32_t)((p+j)*128 + c0*2) ^ (uint32_t)(((p+j) & 7) << 4);
      *(ushort4*)((char*)xs + byteS) = t;
    }
  }
  __syncthreads();

  // ---- Phase B: A-frags via vector LDS reads ----
  short8v afr[4][2];
  #pragma unroll
  for (int t = 0; t < 4; ++t){
    const int row = (t*4 + w)*16 + lc;
    const uint32_t rbase = (uint32_t)(row*128);
    const uint32_t sw = (uint32_t)((row & 7) << 4);
    afr[t][0] = *(const short8v*)((const char*)xs + ((rbase + l4*16) ^ sw));
    afr[t][1] = *(const short8v*)((const char*)xs + ((rbase + 64 + l4*16) ^ sw));
  }
  __syncthreads();   // xs free for Q's D staging

  // ---- Q: MFMA -> D staged to LDS [o][256p] -> 512B linear stores ----
  {
    short8v wf[4][2];
    float bias[4];
    #pragma unroll
    for (int ot = 0; ot < 4; ++ot){
      bias[ot] = Bq[ot*16 + lc];
      #pragma unroll
      for (int ks = 0; ks < 2; ++ks){
        const int base = (ot*16 + lc)*64 + ks*32 + l4*8;
        const float4 q0 = *(const float4*)(Wq + base);
        const float4 q1 = *(const float4*)(Wq + base + 4);
        union { ushort4 u[2]; short8v v; } pk;
        pk.u[0] = f2bf4(q0.x, q0.y, q0.z, q0.w);
        pk.u[1] = f2bf4(q1.x, q1.y, q1.z, q1.w);
        wf[ot][ks] = pk.v;
      }
    }
    #pragma unroll
    for (int t = 0; t < 4; ++t){
      const int pt = (t*4 + w)*16;
      #pragma unroll
      for (int ot = 0; ot < 4; ++ot){
        float4v acc = (float4v){bias[ot], bias[ot], bias[ot], bias[ot]};
        acc = __builtin_amdgcn_mfma_f32_16x16x32_bf16(afr[t][0], wf[ot][0], acc, 0, 0, 0);
        acc = __builtin_amdgcn_mfma_f32_16x16x32_bf16(afr[t][1], wf[ot][1], acc, 0, 0, 0);
        ushort4 u = f2bf4(acc[0], acc[1], acc[2], acc[3]);
        const int o = ot*16 + lc;
        uint32_t byteS = (uint32_t)(o*512 + (pt + l4*4)*2) ^ (uint32_t)((o & 7) << 4);
        *(ushort4*)((char*)xs + byteS) = u;
      }
    }
    __syncthreads();
    for (int i = tid; i < 2048; i += 256){
      const int o = i >> 5, s = i & 31;
      uint32_t byteS = (uint32_t)(o*512 + s*16) ^ (uint32_t)((o & 7) << 4);
      short8v v = *(const short8v*)((const char*)xs + byteS);
      *(short8v*)(Oq + ((size_t)b*64 + o)*PP + p0 + s*8) = v;
    }
  }

  // ---- K: MFMA -> DIRECT tiled stores (512B contiguous per instruction) ----
  {
    short8v wf[4][2];
    float bias[4];
    #pragma unroll
    for (int ot = 0; ot < 4; ++ot){
      bias[ot] = Bk[ot*16 + lc];
      #pragma unroll
      for (int ks = 0; ks < 2; ++ks){
        const int base = (ot*16 + lc)*64 + ks*32 + l4*8;
        const float4 q0 = *(const float4*)(Wk + base);
        const float4 q1 = *(const float4*)(Wk + base + 4);
        union { ushort4 u[2]; short8v v; } pk;
        pk.u[0] = f2bf4(q0.x, q0.y, q0.z, q0.w);
        pk.u[1] = f2bf4(q1.x, q1.y, q1.z, q1.w);
        wf[ot][ks] = pk.v;
      }
    }
    unsigned short* Okb = Ok + (size_t)b * BSTR;
    #pragma unroll
    for (int t = 0; t < 4; ++t){
      const int p16 = bx*16 + t*4 + w;
      #pragma unroll
      for (int ot = 0; ot < 4; ++ot){
        float4v acc = (float4v){bias[ot], bias[ot], bias[ot], bias[ot]};
        acc = __builtin_amdgcn_mfma_f32_16x16x32_bf16(afr[t][0], wf[ot][0], acc, 0, 0, 0);
        acc = __builtin_amdgcn_mfma_f32_16x16x32_bf16(afr[t][1], wf[ot][1], acc, 0, 0, 0);
        ushort4 u = f2bf4(acc[0], acc[1], acc[2], acc[3]);
        const int o = ot*16 + lc;
        *(ushort4*)(Okb + (size_t)p16*1024 + o*16 + l4*4) = u;
      }
    }
  }
}

// ---------------- K2: MFMA attention, K via direct tiled loads (L1/L2-served) ----------------
__global__ __launch_bounds__(448) void k2_attn(
    unsigned short* __restrict__ qF, const unsigned short* __restrict__ qL,
    const unsigned short* __restrict__ kFt, const unsigned short* __restrict__ kLt,
    const float* __restrict__ rgb, const float* __restrict__ fre,
    const float* __restrict__ fad_gamma, const float* __restrict__ lfs_gamma,
    float* __restrict__ stats)
{
  const int bc = blockIdx.x, c = bc & 63, b = bc >> 6;
  const size_t plane = (size_t)bc * PP;
  __shared__ __align__(16) unsigned short alin[PP + 16];
  const int tid = threadIdx.x, lane = tid & 63, w = tid >> 6;
  const int l4 = lane >> 4, lc = lane & 15;

  // q-fragment loads (linear layout, zero-padded K>=112)
  const unsigned short* qFp = qF + plane;
  const unsigned short* qLp = qL + plane;
  const int qrow = w*16 + lc;
  short8v aF[4], aL[4];
  #pragma unroll
  for (int ks = 0; ks < 4; ++ks){
    const int joff = ks*32 + l4*8;
    if ((ks < 3) || (l4 < 2)){
      aF[ks] = *(const short8v*)(qFp + qrow*SS + joff);
      aL[ks] = *(const short8v*)(qLp + qrow*SS + joff);
    } else {
      aF[ks] = (short8v)(short)0;
      aL[ks] = (short8v)(short)0;
    }
  }

  // B-frags: direct tiled loads; jj clamp keeps overflow lanes (k>=112, zeroed on
  // A side) reading valid in-plane bytes (never NaN patterns).
  const unsigned short* kFb = kFt + (size_t)b * BSTR;
  const unsigned short* kLb = kLt + (size_t)b * BSTR;
  float4v acc[7];
  #pragma unroll
  for (int ct = 0; ct < 7; ++ct) acc[ct] = (float4v)0.f;
  #pragma unroll
  for (int ks = 0; ks < 4; ++ks){
    const int j = ks*32 + l4*8;
    const int jj = (j < 112) ? j : 0;
    #pragma unroll
    for (int ct = 0; ct < 7; ++ct){
      const int p = (ct*16 + lc)*SS + jj;
      const uint32_t idx = (uint32_t)(p >> 4)*1024u + (uint32_t)(c*16 + (p & 15));
      short8v bF = *(const short8v*)(kFb + idx);
      short8v bL = *(const short8v*)(kLb + idx);
      acc[ct] = __builtin_amdgcn_mfma_f32_16x16x32_bf16(aF[ks], bF, acc[ct], 0, 0, 0);
      acc[ct] = __builtin_amdgcn_mfma_f32_16x16x32_bf16(aL[ks], bL, acc[ct], 0, 0, 0);
    }
  }

  const float sF = 2.f/(1.f + __expf(-fad_gamma[0])) - 1.f;
  const float sL = 2.f/(1.f + __expf(-lfs_gamma[0])) - 1.f;
  unsigned short* attnP = qF + plane;   // overwrite own q-plane (race-free)

  #pragma unroll
  for (int r = 0; r < 4; ++r){
    const int i = w*16 + l4*4 + r;
    float v[7];
    #pragma unroll
    for (int ct = 0; ct < 7; ++ct) v[ct] = acc[ct][r];
    float m = fmaxf(fmaxf(fmaxf(v[0],v[1]),fmaxf(v[2],v[3])), fmaxf(fmaxf(v[4],v[5]),v[6]));
    #pragma unroll
    for (int off = 8; off; off >>= 1) m = fmaxf(m, __shfl_xor(m, off, 64));
    float e[7]; float s = 0.f;
    #pragma unroll
    for (int ct = 0; ct < 7; ++ct){ e[ct] = __expf(v[ct] - m); s += e[ct]; }
    #pragma unroll
    for (int off = 8; off; off >>= 1) s += __shfl_xor(s, off, 64);
    const float inv = 1.f / s;
    #pragma unroll
    for (int ct = 0; ct < 7; ++ct)
      alin[i*SS + ct*16 + lc] = f2bf(e[ct] * inv);
  }
  __syncthreads();

  // coalesced pass: attn write (512B/instr) + stats from fp32 inputs
  float ls1 = 0.f, lq1 = 0.f, ls2 = 0.f, lq2 = 0.f;
  #pragma unroll
  for (int t = 0; t < 7; ++t){
    const int i4 = tid + t*448;
    ushort4 av = *(const ushort4*)(alin + i4*4);
    *(ushort4*)(attnP + (size_t)i4*4) = av;
    float4 fr = *(const float4*)(fre + plane + (size_t)i4*4);
    float4 rg = *(const float4*)(rgb + plane + (size_t)i4*4);
    const unsigned short* ap = &av.x;
    const float fp[4] = {fr.x, fr.y, fr.z, fr.w};
    const float rp[4] = {rg.x, rg.y, rg.z, rg.w};
    #pragma unroll
    for (int j = 0; j < 4; ++j){
      float a = bf2f(ap[j]);
      float v1 = fp[j] * a * sL;
      float v2 = rp[j] * a * sF;
      ls1 += v1; lq1 += v1*v1; ls2 += v2; lq2 += v2*v2;
    }
  }
  #pragma unroll
  for (int off = 32; off; off >>= 1){
    ls1 += __shfl_xor(ls1, off, 64);
    lq1 += __shfl_xor(lq1, off, 64);
    ls2 += __shfl_xor(ls2, off, 64);
    lq2 += __shfl_xor(lq2, off, 64);
  }
  if (lane == 0){
    atomicAdd(&stats[c],       ls1);
    atomicAdd(&stats[64 + c],  lq1);
    atomicAdd(&stats[128 + c], ls2);
    atomicAdd(&stats[192 + c], lq2);
  }
}

// ---------------- K3: bn1 stats -> affine ----------------
__global__ void k3_affine1(const float* __restrict__ stats,
    const float* __restrict__ fad_cw, const float* __restrict__ fad_bg, const float* __restrict__ fad_bb,
    const float* __restrict__ lfs_cw, const float* __restrict__ lfs_bg, const float* __restrict__ lfs_bb,
    float* __restrict__ AB)
{
  int c = threadIdx.x;
  if (c >= 64) return;
  const float n = 401408.f;
  {
    float m1 = stats[c]/n, v1 = stats[64+c]/n - (stats[c]/n)*(stats[c]/n);
    float cw = fad_cw[c], g = fad_bg[c];
    float rs = rsqrtf(cw*cw*v1 + EPSV);
    AB[c]      = cw*rs*g;
    AB[64 + c] = -cw*m1*rs*g + fad_bb[c];
  }
  {
    float m2 = stats[128+c]/n, v2 = stats[192+c]/n - (stats[128+c]/n)*(stats[128+c]/n);
    float cw = lfs_cw[c], g = lfs_bg[c];
    float rs = rsqrtf(cw*cw*v2 + EPSV);
    AB[128 + c] = cw*rs*g;
    AB[192 + c] = -cw*m2*rs*g + lfs_bb[c];
  }
}

// ---------------- K4: y in-flight + pooling + per-plane stats ----------------
__global__ __launch_bounds__(512) void k4_fuse(
    const unsigned short* __restrict__ attn,
    const float* __restrict__ rgb, const float* __restrict__ fre,
    const float* __restrict__ AB1,
    const float* __restrict__ fad_gamma, const float* __restrict__ lfs_gamma,
    float* __restrict__ avgstat, float* __restrict__ maxstat,
    float4* __restrict__ planeStats)
{
  const int bc = blockIdx.x, b = bc >> 6, c = bc & 63;
  const size_t plane = (size_t)bc * PP;
  __shared__ unsigned short ys[2][112][113];
  __shared__ float redA[8][4];
  __shared__ float redS[8], redM[8];
  const int tid = threadIdx.x, lane = tid & 63, w = tid >> 6;
  const float sF = 2.f/(1.f + __expf(-fad_gamma[0])) - 1.f;
  const float sL = 2.f/(1.f + __expf(-lfs_gamma[0])) - 1.f;
  const float A1 = AB1[c], B1 = AB1[64+c], A2 = AB1[128+c], B2 = AB1[192+c];
  float s0 = 0.f, q0 = 0.f, s1 = 0.f, q1 = 0.f;

  for (int i4 = tid; i4 < 3136; i4 += 512){
    ushort4 av = *(const ushort4*)(attn + plane + (size_t)i4*4);
    float4 rg = *(const float4*)(rgb + plane + (size_t)i4*4);
    float4 fr = *(const float4*)(fre + plane + (size_t)i4*4);
    float aa[4] = {bf2f(av.x), bf2f(av.y), bf2f(av.z), bf2f(av.w)};
    float rr[4] = {rg.x, rg.y, rg.z, rg.w};
    float ff[4] = {fr.x, fr.y, fr.z, fr.w};
    int r = i4 / 28, c0 = (i4 % 28) * 4;
    float y0[4], y1[4];
    #pragma unroll
    for (int j = 0; j < 4; ++j){
      float t1 = ff[j]*aa[j]*sL;
      float t2 = rr[j]*aa[j]*sF;
      y0[j] = rr[j] + A1*t1 + B1;
      y1[j] = ff[j] + A2*t2 + B2;
      s0 += y0[j]; q0 += y0[j]*y0[j];
      s1 += y1[j]; q1 += y1[j]*y1[j];
    }
    *(ushort4*)(&ys[0][r][c0]) = f2bf4(y0[0], y0[1], y0[2], y0[3]);
    *(ushort4*)(&ys[1][r][c0]) = f2bf4(y1[0], y1[1], y1[2], y1[3]);
  }
  #pragma unroll
  for (int off = 32; off; off >>= 1){
    s0 += __shfl_xor(s0, off, 64); q0 += __shfl_xor(q0, off, 64);
    s1 += __shfl_xor(s1, off, 64); q1 += __shfl_xor(q1, off, 64);
  }
  if (lane == 0){ redA[w][0] = s0; redA[w][1] = q0; redA[w][2] = s1; redA[w][3] = q1; }
  __syncthreads();
  if (tid == 0){
    float a0=0,a1=0,a2=0,a3=0;
    for (int i = 0; i < 8; ++i){ a0+=redA[i][0]; a1+=redA[i][1]; a2+=redA[i][2]; a3+=redA[i][3]; }
    float4 ps = {a0,a1,a2,a3};
    planeStats[bc] = ps;
  }
  __syncthreads();

  const int kk[3] = {3,5,7};
  const int gg[3] = {37,22,16};
  for (int pl = 0; pl < 2; ++pl){
    const int cc = pl*64 + c;
    for (int ki = 0; ki < 3; ++ki){
      const int k = kk[ki], g = gg[ki];
      float sumAll = 0.f, mx = -3.0e38f;
      for (int win = tid; win < g*g; win += 512){
        int wy = win / g, wx = win % g;
        float s = 0.f;
        for (int dy = 0; dy < k; ++dy)
          for (int dx = 0; dx < k; ++dx)
            s += bf2f(ys[pl][wy*k+dy][wx*k+dx]);
        sumAll += s; mx = fmaxf(mx, s);
      }
      #pragma unroll
      for (int off = 32; off; off >>= 1){
        sumAll += __shfl_xor(sumAll, off, 64);
        mx = fmaxf(mx, __shfl_xor(mx, off, 64));
      }
      if (lane == 0){ redS[w] = sumAll; redM[w] = mx; }
      __syncthreads();
      if (tid == 0){
        float st = 0.f, mt = -3.0e38f;
        for (int i = 0; i < 8; ++i){ st += redS[i]; mt = fmaxf(mt, redM[i]); }
        int idx = (b*128 + cc)*3 + ki;
        avgstat[idx] = st / (float)(k*k*g*g);
        maxstat[idx] = mt / (float)(k*k);
      }
      __syncthreads();
    }
  }
}

// ---------------- K6: channel-attention MLP ----------------
__global__ void k6_mlp(const float* __restrict__ avgstat, const float* __restrict__ maxstat,
    const float* __restrict__ lin1, const float* __restrict__ lin2,
    const float* __restrict__ w1, const float* __restrict__ w2,
    float* __restrict__ ca)
{
  const int b = blockIdx.x, tid = threadIdx.x; // 128 threads
  __shared__ float sa[128], sm[128], hA[16], hM[16];
  int idx = (b*128 + tid)*3;
  sa[tid] = avgstat[idx]*lin1[0] + avgstat[idx+1]*lin1[1] + avgstat[idx+2]*lin1[2];
  sm[tid] = maxstat[idx]*lin2[0] + maxstat[idx+1]*lin2[1] + maxstat[idx+2]*lin2[2];
  __syncthreads();
  if (tid < 16){
    float ha = 0.f, hm = 0.f;
    for (int c2 = 0; c2 < 128; ++c2){
      ha += w1[tid*128 + c2]*sa[c2];
      hm += w1[tid*128 + c2]*sm[c2];
    }
    hA[tid] = fmaxf(ha, 0.f); hM[tid] = fmaxf(hm, 0.f);
  }
  __syncthreads();
  float o = 0.f;
  for (int r = 0; r < 16; ++r) o += w2[tid*16 + r]*(hA[r] + hM[r]);
  ca[b*128 + tid] = 1.f/(1.f + __expf(-o));
}

// ---------------- K8: final bn affine from per-plane stats + ca ----------------
__global__ void k8_affineF(const float4* __restrict__ planeStats, const float* __restrict__ ca,
    const float* __restrict__ rgb_cw, const float* __restrict__ rgb_bg, const float* __restrict__ rgb_bb,
    const float* __restrict__ fre_cw, const float* __restrict__ fre_bg, const float* __restrict__ fre_bb,
    float* __restrict__ ABF)
{
  int t = threadIdx.x;
  if (t >= 128) return;
  int z = t >> 6, c = t & 63;
  float S = 0.f, Q = 0.f;
  for (int b = 0; b < 32; ++b){
    float4 ps = planeStats[b*64 + c];
    float sc = ca[b*128 + t];
    float sp = z ? ps.z : ps.x;
    float qp = z ? ps.w : ps.y;
    S += sc*sp; Q += sc*sc*qp;
  }
  const float n = 401408.f;
  float m = S/n, v = Q/n - m*m;
  float cw = z ? fre_cw[c] : rgb_cw[c];
  float g  = z ? fre_bg[c] : rgb_bg[c];
  float bb = z ? fre_bb[c] : rgb_bb[c];
  float rs = rsqrtf(cw*cw*v + EPSV);
  ABF[z*128 + c]      = cw*rs*g;
  ABF[z*128 + 64 + c] = -cw*m*rs*g + bb;
}

// ---------------- K9: recompute y from attn, write both outputs ----------------
__global__ __launch_bounds__(256) void k9_out(
    const unsigned short* __restrict__ attn,
    const float* __restrict__ rgb, const float* __restrict__ fre,
    const float* __restrict__ AB1,
    const float* __restrict__ fad_gamma, const float* __restrict__ lfs_gamma,
    const float* __restrict__ ca, const float* __restrict__ ABF,
    float* __restrict__ out)
{
  const int c = blockIdx.x, b = blockIdx.y;
  const size_t plane = ((size_t)b*64 + c)*PP;
  const float sF = 2.f/(1.f + __expf(-fad_gamma[0])) - 1.f;
  const float sL = 2.f/(1.f + __expf(-lfs_gamma[0])) - 1.f;
  const float A1 = AB1[c], B1 = AB1[64+c], A2 = AB1[128+c], B2 = AB1[192+c];
  const float r_c = ca[b*128 + c], f_c = ca[b*128 + 64 + c];
  const float mul0 = 1.f + ABF[c]*r_c,        add0 = ABF[64 + c];
  const float mul1 = 1.f + ABF[128 + c]*f_c,  add1 = ABF[192 + c];
  float* o0 = out + plane;
  float* o1 = out + NE + plane;
  for (int i4 = threadIdx.x; i4 < 3136; i4 += 256){
    ushort4 av = *(const ushort4*)(attn + plane + (size_t)i4*4);
    float4 rg = *(const float4*)(rgb + plane + (size_t)i4*4);
    float4 fr = *(const float4*)(fre + plane + (size_t)i4*4);
    float aa[4] = {bf2f(av.x), bf2f(av.y), bf2f(av.z), bf2f(av.w)};
    float rr[4] = {rg.x, rg.y, rg.z, rg.w};
    float ff[4] = {fr.x, fr.y, fr.z, fr.w};
    float4 v0, v1;
    float* p0 = &v0.x; float* p1 = &v1.x;
    #pragma unroll
    for (int j = 0; j < 4; ++j){
      float t1 = ff[j]*aa[j]*sL;
      float t2 = rr[j]*aa[j]*sF;
      float y0 = rr[j] + A1*t1 + B1;
      float y1 = ff[j] + A2*t2 + B2;
      p0[j] = y0*mul0 + add0;
      p1[j] = y1*mul1 + add1;
    }
    *(float4*)(&o0[(size_t)i4*4]) = v0;
    *(float4*)(&o1[(size_t)i4*4]) = v1;
  }
}

extern "C" void kernel_launch(void* const* d_in, const int* in_sizes, int n_in,
                              void* d_out, int out_size, void* d_ws, size_t ws_size,
                              hipStream_t stream)
{
  (void)in_sizes; (void)n_in; (void)out_size; (void)ws_size;
  const float* rgb      = (const float*)d_in[0];
  const float* fre      = (const float*)d_in[1];
  const float* wq_fad   = (const float*)d_in[2];
  const float* bq_fad   = (const float*)d_in[3];
  const float* wq_lfs   = (const float*)d_in[4];
  const float* bq_lfs   = (const float*)d_in[5];
  const float* wk_fad   = (const float*)d_in[6];
  const float* bk_fad   = (const float*)d_in[7];
  const float* wk_lfs   = (const float*)d_in[8];
  const float* bk_lfs   = (const float*)d_in[9];
  const float* fad_gamma= (const float*)d_in[10];
  const float* lfs_gamma= (const float*)d_in[11];
  const float* fad_cw   = (const float*)d_in[12];
  const float* fad_bg   = (const float*)d_in[14];
  const float* fad_bb   = (const float*)d_in[15];
  const float* lfs_cw   = (const float*)d_in[16];
  const float* lfs_bg   = (const float*)d_in[18];
  const float* lfs_bb   = (const float*)d_in[19];
  const float* lin1_w   = (const float*)d_in[20];
  const float* lin2_w   = (const float*)d_in[21];
  const float* mlp_w1   = (const float*)d_in[22];
  const float* mlp_w2   = (const float*)d_in[23];
  const float* rgb_cw   = (const float*)d_in[24];
  const float* rgb_bg   = (const float*)d_in[26];
  const float* rgb_bb   = (const float*)d_in[27];
  const float* fre_cw   = (const float*)d_in[28];
  const float* fre_bg   = (const float*)d_in[30];
  const float* fre_bb   = (const float*)d_in[31];

  char* ws = (char*)d_ws;
  unsigned short* qF  = (unsigned short*)(ws);          // linear; becomes attn after k2
  unsigned short* qL  = (unsigned short*)(ws + 2*NE);   // linear
  unsigned short* kFt = (unsigned short*)(ws + 4*NE);   // TILED [b][p16][c][16]
  unsigned short* kLt = (unsigned short*)(ws + 6*NE);   // TILED
  float* sbase = (float*)(ws + 8*NE);
  float* stats      = sbase;               // [0..255]   bn1 atomics (memset)
  float* AB1        = sbase + 256;
  float* avgstat    = sbase + 512;
  float* maxstat    = sbase + 12800;
  float* ca         = sbase + 25088;
  float* ABF        = sbase + 29184;
  float4* planeStats= (float4*)(sbase + 29440);

  hipMemsetAsync(stats, 0, 256*sizeof(float), stream);

  k1_conv<<<dim3(49,32,2), dim3(256), 0, stream>>>(rgb, fre,
      wq_fad, bq_fad, wk_fad, bk_fad, wq_lfs, bq_lfs, wk_lfs, bk_lfs,
      qF, kFt, qL, kLt);
  k2_attn<<<dim3(2048), dim3(448), 0, stream>>>(qF, qL, kFt, kLt,
      rgb, fre, fad_gamma, lfs_gamma, stats);
  k3_affine1<<<dim3(1), dim3(64), 0, stream>>>(stats,
      fad_cw, fad_bg, fad_bb, lfs_cw, lfs_bg, lfs_bb, AB1);
  k4_fuse<<<dim3(2048), dim3(512), 0, stream>>>((const unsigned short*)qF,
      rgb, fre, AB1, fad_gamma, lfs_gamma, avgstat, maxstat, planeStats);
  k6_mlp<<<dim3(32), dim3(128), 0, stream>>>(avgstat, maxstat,
      lin1_w, lin2_w, mlp_w1, mlp_w2, ca);
  k8_affineF<<<dim3(1), dim3(128), 0, stream>>>(planeStats, ca,
      rgb_cw, rgb_bg, rgb_bb, fre_cw, fre_bg, fre_bb, ABF);
  k9_out<<<dim3(64,32), dim3(256), 0, stream>>>((const unsigned short*)qF,
      rgb, fre, AB1, fad_gamma, lfs_gamma, ca, ABF, (float*)d_out);
}

// Round 14
// 427.993 us; speedup vs baseline: 1.3088x; 1.3088x over previous
//
#include <hip/hip_runtime.h>
#include <hip/hip_bf16.h>
#include <stdint.h>

#define NE 25690112ull   // 32*64*112*112
#define PP 12544         // 112*112
#define SS 112
#define EPSV 1e-5f

typedef __attribute__((ext_vector_type(8))) short short8v;
typedef __attribute__((ext_vector_type(4))) float float4v;

__device__ __forceinline__ unsigned short f2bf(float x){
  union { __hip_bfloat16 h; unsigned short u; } cv;
  cv.h = __float2bfloat16(x);
  return cv.u;
}
__device__ __forceinline__ ushort4 f2bf4(float a, float b, float c, float d){
  union { __hip_bfloat162 h2[2]; ushort4 u; } cv;
  cv.h2[0] = __float22bfloat162_rn(make_float2(a, b));
  cv.h2[1] = __float22bfloat162_rn(make_float2(c, d));
  return cv.u;
}
__device__ __forceinline__ float bf2f(unsigned short u){ return __uint_as_float(((uint32_t)u) << 16); }

// ---------------- K1: conv1x1 via MFMA, Q/K split into independent blocks ----------------
// blockIdx.z in [0,4): zi = z&1 selects input (rgb/fre), arr = z>>1 selects Q or K.
// Per block: Phase A stage X tile (bf16, [p][c] swizzled), Phase B A-frags,
// then ONE array's MFMA -> D staged to LDS [o][256p] -> 512B-coalesced stores.
__global__ __launch_bounds__(256) void k1_conv(
    const float* __restrict__ rgb, const float* __restrict__ fre,
    const float* __restrict__ wq_fad, const float* __restrict__ bq_fad,
    const float* __restrict__ wk_fad, const float* __restrict__ bk_fad,
    const float* __restrict__ wq_lfs, const float* __restrict__ bq_lfs,
    const float* __restrict__ wk_lfs, const float* __restrict__ bk_lfs,
    unsigned short* __restrict__ qF, unsigned short* __restrict__ kF,
    unsigned short* __restrict__ qL, unsigned short* __restrict__ kL)
{
  const int bx = blockIdx.x, b = blockIdx.y, zz = blockIdx.z;
  const int zi = zz & 1, arr = zz >> 1;
  const float* X = zi ? fre : rgb;
  const float* W;
  const float* Bi;
  unsigned short* O;
  if (arr == 0){
    W = zi ? wq_lfs : wq_fad;  Bi = zi ? bq_lfs : bq_fad;  O = zi ? qL : qF;
  } else {
    W = zi ? wk_lfs : wk_fad;  Bi = zi ? bk_lfs : bk_fad;  O = zi ? kL : kF;
  }

  __shared__ __align__(16) unsigned short xs[256 * 64];   // 32 KB

  const int tid = threadIdx.x, lane = tid & 63, w = tid >> 6;
  const int lc = lane & 15, l4 = lane >> 4;

  // ---- Phase A: stage 256p x 64c, 4x4 micro-transpose into [p][c] swizzled ----
  const int p0 = bx*256;
  const size_t xbase = (size_t)b * 64 * PP;
  const int c0 = (tid & 15) * 4;
  const int pq = (tid >> 4) * 4;
  #pragma unroll
  for (int itp = 0; itp < 4; ++itp){
    const int p = itp*64 + pq;
    float4 xr[4];
    #pragma unroll
    for (int k = 0; k < 4; ++k)
      xr[k] = *(const float4*)(X + xbase + (size_t)(c0+k)*PP + p0 + p);
    const float* v0 = &xr[0].x;
    const float* v1 = &xr[1].x;
    const float* v2 = &xr[2].x;
    const float* v3 = &xr[3].x;
    #pragma unroll
    for (int j = 0; j < 4; ++j){
      ushort4 t = f2bf4(v0[j], v1[j], v2[j], v3[j]);
      uint32_t byteS = (uint32_t)((p+j)*128 + c0*2) ^ (uint32_t)(((p+j) & 7) << 4);
      *(ushort4*)((char*)xs + byteS) = t;
    }
  }
  __syncthreads();

  // ---- Phase B: A-frags via vector LDS reads (xs free afterwards) ----
  short8v afr[4][2];
  #pragma unroll
  for (int t = 0; t < 4; ++t){
    const int row = (t*4 + w)*16 + lc;
    const uint32_t rbase = (uint32_t)(row*128);
    const uint32_t sw = (uint32_t)((row & 7) << 4);
    afr[t][0] = *(const short8v*)((const char*)xs + ((rbase + l4*16) ^ sw));
    afr[t][1] = *(const short8v*)((const char*)xs + ((rbase + 64 + l4*16) ^ sw));
  }
  __syncthreads();

  // ---- Phase C: this array's weights -> MFMA -> D to LDS [o][256p] -> stores ----
  short8v wf[4][2];
  float bias[4];
  #pragma unroll
  for (int ot = 0; ot < 4; ++ot){
    bias[ot] = Bi[ot*16 + lc];
    #pragma unroll
    for (int ks = 0; ks < 2; ++ks){
      const int base = (ot*16 + lc)*64 + ks*32 + l4*8;
      const float4 q0 = *(const float4*)(W + base);
      const float4 q1 = *(const float4*)(W + base + 4);
      union { ushort4 u[2]; short8v v; } pk;
      pk.u[0] = f2bf4(q0.x, q0.y, q0.z, q0.w);
      pk.u[1] = f2bf4(q1.x, q1.y, q1.z, q1.w);
      wf[ot][ks] = pk.v;
    }
  }
  #pragma unroll
  for (int t = 0; t < 4; ++t){
    const int pt = (t*4 + w)*16;
    #pragma unroll
    for (int ot = 0; ot < 4; ++ot){
      float4v acc = (float4v){bias[ot], bias[ot], bias[ot], bias[ot]};
      acc = __builtin_amdgcn_mfma_f32_16x16x32_bf16(afr[t][0], wf[ot][0], acc, 0, 0, 0);
      acc = __builtin_amdgcn_mfma_f32_16x16x32_bf16(afr[t][1], wf[ot][1], acc, 0, 0, 0);
      ushort4 u = f2bf4(acc[0], acc[1], acc[2], acc[3]);
      const int o = ot*16 + lc;
      uint32_t byteS = (uint32_t)(o*512 + (pt + l4*4)*2) ^ (uint32_t)((o & 7) << 4);
      *(ushort4*)((char*)xs + byteS) = u;
    }
  }
  __syncthreads();
  for (int i = tid; i < 2048; i += 256){
    const int o = i >> 5, s = i & 31;
    uint32_t byteS = (uint32_t)(o*512 + s*16) ^ (uint32_t)((o & 7) << 4);
    short8v v = *(const short8v*)((const char*)xs + byteS);
    *(short8v*)(O + ((size_t)b*64 + o)*PP + p0 + s*8) = v;
  }
}

// ---------------- K2: MFMA attention (R9 form: linear LDS K staging) ----------------
__global__ __launch_bounds__(448) void k2_attn(
    unsigned short* __restrict__ qF, const unsigned short* __restrict__ qL,
    const unsigned short* __restrict__ kF, const unsigned short* __restrict__ kL,
    const float* __restrict__ rgb, const float* __restrict__ fre,
    const float* __restrict__ fad_gamma, const float* __restrict__ lfs_gamma,
    float* __restrict__ stats)
{
  const int bc = blockIdx.x, c = bc & 63;
  const size_t plane = (size_t)bc * PP;
  __shared__ __align__(16) unsigned short ksF[PP + 16];
  __shared__ __align__(16) unsigned short ksL[PP + 16];
  const int tid = threadIdx.x, lane = tid & 63, w = tid >> 6;
  const int l4 = lane >> 4, lc = lane & 15;

  const unsigned short* qFp = qF + plane;
  const unsigned short* qLp = qL + plane;
  const int qrow = w*16 + lc;
  short8v aF[4], aL[4];
  #pragma unroll
  for (int ks = 0; ks < 4; ++ks){
    const int joff = ks*32 + l4*8;
    if ((ks < 3) || (l4 < 2)){
      aF[ks] = *(const short8v*)(qFp + qrow*SS + joff);
      aL[ks] = *(const short8v*)(qLp + qrow*SS + joff);
    } else {
      aF[ks] = (short8v)(short)0;
      aL[ks] = (short8v)(short)0;
    }
  }

  const uint32_t* kFu = (const uint32_t*)kF + plane/2;
  const uint32_t* kLu = (const uint32_t*)kL + plane/2;
  uint32_t* d0 = (uint32_t*)ksF;
  uint32_t* d1 = (uint32_t*)ksL;
  #pragma unroll
  for (int t = 0; t < 14; ++t){
    const int i = tid + t*448;
    d0[i] = kFu[i];
    d1[i] = kLu[i];
  }
  __syncthreads();

  float4v acc[7];
  #pragma unroll
  for (int ct = 0; ct < 7; ++ct) acc[ct] = (float4v)0.f;
  #pragma unroll
  for (int ks = 0; ks < 4; ++ks){
    #pragma unroll
    for (int ct = 0; ct < 7; ++ct){
      const uint32_t off = (uint32_t)((ct*16 + lc)*224 + ks*64 + l4*16);
      short8v bF = *(const short8v*)((const char*)ksF + off);
      short8v bL = *(const short8v*)((const char*)ksL + off);
      acc[ct] = __builtin_amdgcn_mfma_f32_16x16x32_bf16(aF[ks], bF, acc[ct], 0, 0, 0);
      acc[ct] = __builtin_amdgcn_mfma_f32_16x16x32_bf16(aL[ks], bL, acc[ct], 0, 0, 0);
    }
  }

  const float sF = 2.f/(1.f + __expf(-fad_gamma[0])) - 1.f;
  const float sL = 2.f/(1.f + __expf(-lfs_gamma[0])) - 1.f;
  unsigned short* attnP = qF + plane;
  unsigned short* alin = ksF;

  __syncthreads();
  #pragma unroll
  for (int r = 0; r < 4; ++r){
    const int i = w*16 + l4*4 + r;
    float v[7];
    #pragma unroll
    for (int ct = 0; ct < 7; ++ct) v[ct] = acc[ct][r];
    float m = fmaxf(fmaxf(fmaxf(v[0],v[1]),fmaxf(v[2],v[3])), fmaxf(fmaxf(v[4],v[5]),v[6]));
    #pragma unroll
    for (int off = 8; off; off >>= 1) m = fmaxf(m, __shfl_xor(m, off, 64));
    float e[7]; float s = 0.f;
    #pragma unroll
    for (int ct = 0; ct < 7; ++ct){ e[ct] = __expf(v[ct] - m); s += e[ct]; }
    #pragma unroll
    for (int off = 8; off; off >>= 1) s += __shfl_xor(s, off, 64);
    const float inv = 1.f / s;
    #pragma unroll
    for (int ct = 0; ct < 7; ++ct)
      alin[i*SS + ct*16 + lc] = f2bf(e[ct] * inv);
  }
  __syncthreads();

  float ls1 = 0.f, lq1 = 0.f, ls2 = 0.f, lq2 = 0.f;
  #pragma unroll
  for (int t = 0; t < 7; ++t){
    const int i4 = tid + t*448;
    ushort4 av = *(const ushort4*)(alin + i4*4);
    *(ushort4*)(attnP + (size_t)i4*4) = av;
    float4 fr = *(const float4*)(fre + plane + (size_t)i4*4);
    float4 rg = *(const float4*)(rgb + plane + (size_t)i4*4);
    const unsigned short* ap = &av.x;
    const float fp[4] = {fr.x, fr.y, fr.z, fr.w};
    const float rp[4] = {rg.x, rg.y, rg.z, rg.w};
    #pragma unroll
    for (int j = 0; j < 4; ++j){
      float a = bf2f(ap[j]);
      float v1 = fp[j] * a * sL;
      float v2 = rp[j] * a * sF;
      ls1 += v1; lq1 += v1*v1; ls2 += v2; lq2 += v2*v2;
    }
  }
  #pragma unroll
  for (int off = 32; off; off >>= 1){
    ls1 += __shfl_xor(ls1, off, 64);
    lq1 += __shfl_xor(lq1, off, 64);
    ls2 += __shfl_xor(ls2, off, 64);
    lq2 += __shfl_xor(lq2, off, 64);
  }
  if (lane == 0){
    atomicAdd(&stats[c],       ls1);
    atomicAdd(&stats[64 + c],  lq1);
    atomicAdd(&stats[128 + c], ls2);
    atomicAdd(&stats[192 + c], lq2);
  }
}

// ---------------- K3: bn1 stats -> affine ----------------
__global__ void k3_affine1(const float* __restrict__ stats,
    const float* __restrict__ fad_cw, const float* __restrict__ fad_bg, const float* __restrict__ fad_bb,
    const float* __restrict__ lfs_cw, const float* __restrict__ lfs_bg, const float* __restrict__ lfs_bb,
    float* __restrict__ AB)
{
  int c = threadIdx.x;
  if (c >= 64) return;
  const float n = 401408.f;
  {
    float m1 = stats[c]/n, v1 = stats[64+c]/n - (stats[c]/n)*(stats[c]/n);
    float cw = fad_cw[c], g = fad_bg[c];
    float rs = rsqrtf(cw*cw*v1 + EPSV);
    AB[c]      = cw*rs*g;
    AB[64 + c] = -cw*m1*rs*g + fad_bb[c];
  }
  {
    float m2 = stats[128+c]/n, v2 = stats[192+c]/n - (stats[128+c]/n)*(stats[128+c]/n);
    float cw = lfs_cw[c], g = lfs_bg[c];
    float rs = rsqrtf(cw*cw*v2 + EPSV);
    AB[128 + c] = cw*rs*g;
    AB[192 + c] = -cw*m2*rs*g + lfs_bb[c];
  }
}

// ---------------- K4: y in-flight + pooling + per-plane stats ----------------
__global__ __launch_bounds__(512) void k4_fuse(
    const unsigned short* __restrict__ attn,
    const float* __restrict__ rgb, const float* __restrict__ fre,
    const float* __restrict__ AB1,
    const float* __restrict__ fad_gamma, const float* __restrict__ lfs_gamma,
    float* __restrict__ avgstat, float* __restrict__ maxstat,
    float4* __restrict__ planeStats)
{
  const int bc = blockIdx.x, b = bc >> 6, c = bc & 63;
  const size_t plane = (size_t)bc * PP;
  __shared__ unsigned short ys[2][112][113];
  __shared__ float redA[8][4];
  __shared__ float redS[8], redM[8];
  const int tid = threadIdx.x, lane = tid & 63, w = tid >> 6;
  const float sF = 2.f/(1.f + __expf(-fad_gamma[0])) - 1.f;
  const float sL = 2.f/(1.f + __expf(-lfs_gamma[0])) - 1.f;
  const float A1 = AB1[c], B1 = AB1[64+c], A2 = AB1[128+c], B2 = AB1[192+c];
  float s0 = 0.f, q0 = 0.f, s1 = 0.f, q1 = 0.f;

  for (int i4 = tid; i4 < 3136; i4 += 512){
    ushort4 av = *(const ushort4*)(attn + plane + (size_t)i4*4);
    float4 rg = *(const float4*)(rgb + plane + (size_t)i4*4);
    float4 fr = *(const float4*)(fre + plane + (size_t)i4*4);
    float aa[4] = {bf2f(av.x), bf2f(av.y), bf2f(av.z), bf2f(av.w)};
    float rr[4] = {rg.x, rg.y, rg.z, rg.w};
    float ff[4] = {fr.x, fr.y, fr.z, fr.w};
    int r = i4 / 28, c0 = (i4 % 28) * 4;
    float y0[4], y1[4];
    #pragma unroll
    for (int j = 0; j < 4; ++j){
      float t1 = ff[j]*aa[j]*sL;
      float t2 = rr[j]*aa[j]*sF;
      y0[j] = rr[j] + A1*t1 + B1;
      y1[j] = ff[j] + A2*t2 + B2;
      s0 += y0[j]; q0 += y0[j]*y0[j];
      s1 += y1[j]; q1 += y1[j]*y1[j];
    }
    *(ushort4*)(&ys[0][r][c0]) = f2bf4(y0[0], y0[1], y0[2], y0[3]);
    *(ushort4*)(&ys[1][r][c0]) = f2bf4(y1[0], y1[1], y1[2], y1[3]);
  }
  #pragma unroll
  for (int off = 32; off; off >>= 1){
    s0 += __shfl_xor(s0, off, 64); q0 += __shfl_xor(q0, off, 64);
    s1 += __shfl_xor(s1, off, 64); q1 += __shfl_xor(q1, off, 64);
  }
  if (lane == 0){ redA[w][0] = s0; redA[w][1] = q0; redA[w][2] = s1; redA[w][3] = q1; }
  __syncthreads();
  if (tid == 0){
    float a0=0,a1=0,a2=0,a3=0;
    for (int i = 0; i < 8; ++i){ a0+=redA[i][0]; a1+=redA[i][1]; a2+=redA[i][2]; a3+=redA[i][3]; }
    float4 ps = {a0,a1,a2,a3};
    planeStats[bc] = ps;
  }
  __syncthreads();

  const int kk[3] = {3,5,7};
  const int gg[3] = {37,22,16};
  for (int pl = 0; pl < 2; ++pl){
    const int cc = pl*64 + c;
    for (int ki = 0; ki < 3; ++ki){
      const int k = kk[ki], g = gg[ki];
      float sumAll = 0.f, mx = -3.0e38f;
      for (int win = tid; win < g*g; win += 512){
        int wy = win / g, wx = win % g;
        float s = 0.f;
        for (int dy = 0; dy < k; ++dy)
          for (int dx = 0; dx < k; ++dx)
            s += bf2f(ys[pl][wy*k+dy][wx*k+dx]);
        sumAll += s; mx = fmaxf(mx, s);
      }
      #pragma unroll
      for (int off = 32; off; off >>= 1){
        sumAll += __shfl_xor(sumAll, off, 64);
        mx = fmaxf(mx, __shfl_xor(mx, off, 64));
      }
      if (lane == 0){ redS[w] = sumAll; redM[w] = mx; }
      __syncthreads();
      if (tid == 0){
        float st = 0.f, mt = -3.0e38f;
        for (int i = 0; i < 8; ++i){ st += redS[i]; mt = fmaxf(mt, redM[i]); }
        int idx = (b*128 + cc)*3 + ki;
        avgstat[idx] = st / (float)(k*k*g*g);
        maxstat[idx] = mt / (float)(k*k);
      }
      __syncthreads();
    }
  }
}

// ---------------- K6: channel-attention MLP ----------------
__global__ void k6_mlp(const float* __restrict__ avgstat, const float* __restrict__ maxstat,
    const float* __restrict__ lin1, const float* __restrict__ lin2,
    const float* __restrict__ w1, const float* __restrict__ w2,
    float* __restrict__ ca)
{
  const int b = blockIdx.x, tid = threadIdx.x; // 128 threads
  __shared__ float sa[128], sm[128], hA[16], hM[16];
  int idx = (b*128 + tid)*3;
  sa[tid] = avgstat[idx]*lin1[0] + avgstat[idx+1]*lin1[1] + avgstat[idx+2]*lin1[2];
  sm[tid] = maxstat[idx]*lin2[0] + maxstat[idx+1]*lin2[1] + maxstat[idx+2]*lin2[2];
  __syncthreads();
  if (tid < 16){
    float ha = 0.f, hm = 0.f;
    for (int c2 = 0; c2 < 128; ++c2){
      ha += w1[tid*128 + c2]*sa[c2];
      hm += w1[tid*128 + c2]*sm[c2];
    }
    hA[tid] = fmaxf(ha, 0.f); hM[tid] = fmaxf(hm, 0.f);
  }
  __syncthreads();
  float o = 0.f;
  for (int r = 0; r < 16; ++r) o += w2[tid*16 + r]*(hA[r] + hM[r]);
  ca[b*128 + tid] = 1.f/(1.f + __expf(-o));
}

// ---------------- K8: final bn affine from per-plane stats + ca ----------------
__global__ void k8_affineF(const float4* __restrict__ planeStats, const float* __restrict__ ca,
    const float* __restrict__ rgb_cw, const float* __restrict__ rgb_bg, const float* __restrict__ rgb_bb,
    const float* __restrict__ fre_cw, const float* __restrict__ fre_bg, const float* __restrict__ fre_bb,
    float* __restrict__ ABF)
{
  int t = threadIdx.x;
  if (t >= 128) return;
  int z = t >> 6, c = t & 63;
  float S = 0.f, Q = 0.f;
  for (int b = 0; b < 32; ++b){
    float4 ps = planeStats[b*64 + c];
    float sc = ca[b*128 + t];
    float sp = z ? ps.z : ps.x;
    float qp = z ? ps.w : ps.y;
    S += sc*sp; Q += sc*sc*qp;
  }
  const float n = 401408.f;
  float m = S/n, v = Q/n - m*m;
  float cw = z ? fre_cw[c] : rgb_cw[c];
  float g  = z ? fre_bg[c] : rgb_bg[c];
  float bb = z ? fre_bb[c] : rgb_bb[c];
  float rs = rsqrtf(cw*cw*v + EPSV);
  ABF[z*128 + c]      = cw*rs*g;
  ABF[z*128 + 64 + c] = -cw*m*rs*g + bb;
}

// ---------------- K9: recompute y from attn, write both outputs ----------------
__global__ __launch_bounds__(256) void k9_out(
    const unsigned short* __restrict__ attn,
    const float* __restrict__ rgb, const float* __restrict__ fre,
    const float* __restrict__ AB1,
    const float* __restrict__ fad_gamma, const float* __restrict__ lfs_gamma,
    const float* __restrict__ ca, const float* __restrict__ ABF,
    float* __restrict__ out)
{
  const int c = blockIdx.x, b = blockIdx.y;
  const size_t plane = ((size_t)b*64 + c)*PP;
  const float sF = 2.f/(1.f + __expf(-fad_gamma[0])) - 1.f;
  const float sL = 2.f/(1.f + __expf(-lfs_gamma[0])) - 1.f;
  const float A1 = AB1[c], B1 = AB1[64+c], A2 = AB1[128+c], B2 = AB1[192+c];
  const float r_c = ca[b*128 + c], f_c = ca[b*128 + 64 + c];
  const float mul0 = 1.f + ABF[c]*r_c,        add0 = ABF[64 + c];
  const float mul1 = 1.f + ABF[128 + c]*f_c,  add1 = ABF[192 + c];
  float* o0 = out + plane;
  float* o1 = out + NE + plane;
  for (int i4 = threadIdx.x; i4 < 3136; i4 += 256){
    ushort4 av = *(const ushort4*)(attn + plane + (size_t)i4*4);
    float4 rg = *(const float4*)(rgb + plane + (size_t)i4*4);
    float4 fr = *(const float4*)(fre + plane + (size_t)i4*4);
    float aa[4] = {bf2f(av.x), bf2f(av.y), bf2f(av.z), bf2f(av.w)};
    float rr[4] = {rg.x, rg.y, rg.z, rg.w};
    float ff[4] = {fr.x, fr.y, fr.z, fr.w};
    float4 v0, v1;
    float* p0 = &v0.x; float* p1 = &v1.x;
    #pragma unroll
    for (int j = 0; j < 4; ++j){
      float t1 = ff[j]*aa[j]*sL;
      float t2 = rr[j]*aa[j]*sF;
      float y0 = rr[j] + A1*t1 + B1;
      float y1 = ff[j] + A2*t2 + B2;
      p0[j] = y0*mul0 + add0;
      p1[j] = y1*mul1 + add1;
    }
    *(float4*)(&o0[(size_t)i4*4]) = v0;
    *(float4*)(&o1[(size_t)i4*4]) = v1;
  }
}

extern "C" void kernel_launch(void* const* d_in, const int* in_sizes, int n_in,
                              void* d_out, int out_size, void* d_ws, size_t ws_size,
                              hipStream_t stream)
{
  (void)in_sizes; (void)n_in; (void)out_size; (void)ws_size;
  const float* rgb      = (const float*)d_in[0];
  const float* fre      = (const float*)d_in[1];
  const float* wq_fad   = (const float*)d_in[2];
  const float* bq_fad   = (const float*)d_in[3];
  const float* wq_lfs   = (const float*)d_in[4];
  const float* bq_lfs   = (const float*)d_in[5];
  const float* wk_fad   = (const float*)d_in[6];
  const float* bk_fad   = (const float*)d_in[7];
  const float* wk_lfs   = (const float*)d_in[8];
  const float* bk_lfs   = (const float*)d_in[9];
  const float* fad_gamma= (const float*)d_in[10];
  const float* lfs_gamma= (const float*)d_in[11];
  const float* fad_cw   = (const float*)d_in[12];
  const float* fad_bg   = (const float*)d_in[14];
  const float* fad_bb   = (const float*)d_in[15];
  const float* lfs_cw   = (const float*)d_in[16];
  const float* lfs_bg   = (const float*)d_in[18];
  const float* lfs_bb   = (const float*)d_in[19];
  const float* lin1_w   = (const float*)d_in[20];
  const float* lin2_w   = (const float*)d_in[21];
  const float* mlp_w1   = (const float*)d_in[22];
  const float* mlp_w2   = (const float*)d_in[23];
  const float* rgb_cw   = (const float*)d_in[24];
  const float* rgb_bg   = (const float*)d_in[26];
  const float* rgb_bb   = (const float*)d_in[27];
  const float* fre_cw   = (const float*)d_in[28];
  const float* fre_bg   = (const float*)d_in[30];
  const float* fre_bb   = (const float*)d_in[31];

  char* ws = (char*)d_ws;
  unsigned short* qF = (unsigned short*)(ws);          // becomes attn after k2
  unsigned short* qL = (unsigned short*)(ws + 2*NE);
  unsigned short* kF = (unsigned short*)(ws + 4*NE);
  unsigned short* kL = (unsigned short*)(ws + 6*NE);
  float* sbase = (float*)(ws + 8*NE);
  float* stats      = sbase;               // [0..255]   bn1 atomics (memset)
  float* AB1        = sbase + 256;
  float* avgstat    = sbase + 512;
  float* maxstat    = sbase + 12800;
  float* ca         = sbase + 25088;
  float* ABF        = sbase + 29184;
  float4* planeStats= (float4*)(sbase + 29440);

  hipMemsetAsync(stats, 0, 256*sizeof(float), stream);

  k1_conv<<<dim3(49,32,4), dim3(256), 0, stream>>>(rgb, fre,
      wq_fad, bq_fad, wk_fad, bk_fad, wq_lfs, bq_lfs, wk_lfs, bk_lfs,
      qF, kF, qL, kL);
  k2_attn<<<dim3(2048), dim3(448), 0, stream>>>(qF, qL, kF, kL,
      rgb, fre, fad_gamma, lfs_gamma, stats);
  k3_affine1<<<dim3(1), dim3(64), 0, stream>>>(stats,
      fad_cw, fad_bg, fad_bb, lfs_cw, lfs_bg, lfs_bb, AB1);
  k4_fuse<<<dim3(2048), dim3(512), 0, stream>>>((const unsigned short*)qF,
      rgb, fre, AB1, fad_gamma, lfs_gamma, avgstat, maxstat, planeStats);
  k6_mlp<<<dim3(32), dim3(128), 0, stream>>>(avgstat, maxstat,
      lin1_w, lin2_w, mlp_w1, mlp_w2, ca);
  k8_affineF<<<dim3(1), dim3(128), 0, stream>>>(planeStats, ca,
      rgb_cw, rgb_bg, rgb_bb, fre_cw, fre_bg, fre_bb, ABF);
  k9_out<<<dim3(64,32), dim3(256), 0, stream>>>((const unsigned short*)qF,
      rgb, fre, AB1, fad_gamma, lfs_gamma, ca, ABF, (float*)d_out);
}

// Round 15
// 400.390 us; speedup vs baseline: 1.3990x; 1.0689x over previous
//
#include <hip/hip_runtime.h>
#include <hip/hip_bf16.h>
#include <stdint.h>

#define NE 25690112ull   // 32*64*112*112
#define PP 12544         // 112*112
#define SS 112
#define EPSV 1e-5f

typedef __attribute__((ext_vector_type(8))) short short8v;
typedef __attribute__((ext_vector_type(4))) float float4v;

__device__ __forceinline__ unsigned short f2bf(float x){
  union { __hip_bfloat16 h; unsigned short u; } cv;
  cv.h = __float2bfloat16(x);
  return cv.u;
}
__device__ __forceinline__ ushort4 f2bf4(float a, float b, float c, float d){
  union { __hip_bfloat162 h2[2]; ushort4 u; } cv;
  cv.h2[0] = __float22bfloat162_rn(make_float2(a, b));
  cv.h2[1] = __float22bfloat162_rn(make_float2(c, d));
  return cv.u;
}
__device__ __forceinline__ float bf2f(unsigned short u){ return __uint_as_float(((uint32_t)u) << 16); }

// ---------------- K1: conv1x1 via MFMA, BARRIER-FREE (wave-independent) ----------------
// Each wave owns a 64-p tile and an 8KB private LDS slice. No __syncthreads anywhere:
// intra-wave LDS RAW ordering is compiler-handled (lgkmcnt). Stores fire-and-forget.
__global__ __launch_bounds__(256) void k1_conv(
    const float* __restrict__ rgb, const float* __restrict__ fre,
    const float* __restrict__ wq_fad, const float* __restrict__ bq_fad,
    const float* __restrict__ wk_fad, const float* __restrict__ bk_fad,
    const float* __restrict__ wq_lfs, const float* __restrict__ bq_lfs,
    const float* __restrict__ wk_lfs, const float* __restrict__ bk_lfs,
    unsigned short* __restrict__ qF, unsigned short* __restrict__ kF,
    unsigned short* __restrict__ qL, unsigned short* __restrict__ kL)
{
  const int bx = blockIdx.x, b = blockIdx.y, z = blockIdx.z;
  const float* X  = z ? fre : rgb;
  const float* Wq = z ? wq_lfs : wq_fad;
  const float* Bq = z ? bq_lfs : bq_fad;
  const float* Wk = z ? wk_lfs : wk_fad;
  const float* Bk = z ? bk_lfs : bk_fad;
  unsigned short* Oq = z ? qL : qF;
  unsigned short* Ok = z ? kL : kF;

  __shared__ __align__(16) unsigned short xs[4][4096];   // 8KB per wave, 32KB total

  const int tid = threadIdx.x, lane = tid & 63, w = tid >> 6;
  const int lc = lane & 15, l4 = lane >> 4;
  unsigned short* xw = &xs[w][0];

  const int P0 = (bx*4 + w)*64;          // this wave's 64-p tile
  const size_t xbase = (size_t)b * 64 * PP;

  // ---- Phase A (wave-local): 64p x 64c, 4x4 micro-transpose into [p][c] swizzled ----
  const int c0 = lc * 4;
  const int pq = l4 * 4;
  #pragma unroll
  for (int itp = 0; itp < 4; ++itp){
    const int p = itp*16 + pq;
    float4 xr[4];
    #pragma unroll
    for (int k = 0; k < 4; ++k)
      xr[k] = *(const float4*)(X + xbase + (size_t)(c0+k)*PP + P0 + p);
    const float* v0 = &xr[0].x;
    const float* v1 = &xr[1].x;
    const float* v2 = &xr[2].x;
    const float* v3 = &xr[3].x;
    #pragma unroll
    for (int j = 0; j < 4; ++j){
      ushort4 t = f2bf4(v0[j], v1[j], v2[j], v3[j]);
      uint32_t byteS = (uint32_t)((p+j)*128 + c0*2) ^ (uint32_t)(((p+j) & 7) << 4);
      *(ushort4*)((char*)xw + byteS) = t;
    }
  }

  // ---- Phase B (wave-local): A-frags via ds_read_b128 ----
  short8v afr[4][2];
  #pragma unroll
  for (int t = 0; t < 4; ++t){
    const int row = t*16 + lc;
    const uint32_t rbase = (uint32_t)(row*128);
    const uint32_t sw = (uint32_t)((row & 7) << 4);
    afr[t][0] = *(const short8v*)((const char*)xw + ((rbase + l4*16) ^ sw));
    afr[t][1] = *(const short8v*)((const char*)xw + ((rbase + 64 + l4*16) ^ sw));
  }

  // ---- Phase C (wave-local): per {Q,K}: MFMA -> D to LDS [o][64p] -> 128B-row stores ----
  #pragma unroll
  for (int arr = 0; arr < 2; ++arr){
    const float* W = arr ? Wk : Wq;
    const float* Bi = arr ? Bk : Bq;
    unsigned short* O = arr ? Ok : Oq;
    short8v wf[4][2];
    float bias[4];
    #pragma unroll
    for (int ot = 0; ot < 4; ++ot){
      bias[ot] = Bi[ot*16 + lc];
      #pragma unroll
      for (int ks = 0; ks < 2; ++ks){
        const int base = (ot*16 + lc)*64 + ks*32 + l4*8;
        const float4 q0 = *(const float4*)(W + base);
        const float4 q1 = *(const float4*)(W + base + 4);
        union { ushort4 u[2]; short8v v; } pk;
        pk.u[0] = f2bf4(q0.x, q0.y, q0.z, q0.w);
        pk.u[1] = f2bf4(q1.x, q1.y, q1.z, q1.w);
        wf[ot][ks] = pk.v;
      }
    }
    #pragma unroll
    for (int t = 0; t < 4; ++t){
      #pragma unroll
      for (int ot = 0; ot < 4; ++ot){
        float4v acc = (float4v){bias[ot], bias[ot], bias[ot], bias[ot]};
        acc = __builtin_amdgcn_mfma_f32_16x16x32_bf16(afr[t][0], wf[ot][0], acc, 0, 0, 0);
        acc = __builtin_amdgcn_mfma_f32_16x16x32_bf16(afr[t][1], wf[ot][1], acc, 0, 0, 0);
        ushort4 u = f2bf4(acc[0], acc[1], acc[2], acc[3]);
        const int o = ot*16 + lc;
        uint32_t byteS = (uint32_t)(o*128 + (t*16 + l4*4)*2) ^ (uint32_t)((o & 7) << 4);
        *(ushort4*)((char*)xw + byteS) = u;
      }
    }
    // store: 64 rows x 128B; 8 instrs/wave, 8 contiguous 128B segments each
    #pragma unroll
    for (int i0 = 0; i0 < 512; i0 += 64){
      const int i = i0 + lane;
      const int o = i >> 3, s = i & 7;
      uint32_t byteS = (uint32_t)(o*128 + s*16) ^ (uint32_t)((o & 7) << 4);
      short8v v = *(const short8v*)((const char*)xw + byteS);
      *(short8v*)(O + ((size_t)b*64 + o)*PP + P0 + s*8) = v;
    }
  }
}

// ---------------- K2: MFMA attention (R9 form: linear LDS K staging) ----------------
__global__ __launch_bounds__(448) void k2_attn(
    unsigned short* __restrict__ qF, const unsigned short* __restrict__ qL,
    const unsigned short* __restrict__ kF, const unsigned short* __restrict__ kL,
    const float* __restrict__ rgb, const float* __restrict__ fre,
    const float* __restrict__ fad_gamma, const float* __restrict__ lfs_gamma,
    float* __restrict__ stats)
{
  const int bc = blockIdx.x, c = bc & 63;
  const size_t plane = (size_t)bc * PP;
  __shared__ __align__(16) unsigned short ksF[PP + 16];
  __shared__ __align__(16) unsigned short ksL[PP + 16];
  const int tid = threadIdx.x, lane = tid & 63, w = tid >> 6;
  const int l4 = lane >> 4, lc = lane & 15;

  const unsigned short* qFp = qF + plane;
  const unsigned short* qLp = qL + plane;
  const int qrow = w*16 + lc;
  short8v aF[4], aL[4];
  #pragma unroll
  for (int ks = 0; ks < 4; ++ks){
    const int joff = ks*32 + l4*8;
    if ((ks < 3) || (l4 < 2)){
      aF[ks] = *(const short8v*)(qFp + qrow*SS + joff);
      aL[ks] = *(const short8v*)(qLp + qrow*SS + joff);
    } else {
      aF[ks] = (short8v)(short)0;
      aL[ks] = (short8v)(short)0;
    }
  }

  const uint32_t* kFu = (const uint32_t*)kF + plane/2;
  const uint32_t* kLu = (const uint32_t*)kL + plane/2;
  uint32_t* d0 = (uint32_t*)ksF;
  uint32_t* d1 = (uint32_t*)ksL;
  #pragma unroll
  for (int t = 0; t < 14; ++t){
    const int i = tid + t*448;
    d0[i] = kFu[i];
    d1[i] = kLu[i];
  }
  __syncthreads();

  float4v acc[7];
  #pragma unroll
  for (int ct = 0; ct < 7; ++ct) acc[ct] = (float4v)0.f;
  #pragma unroll
  for (int ks = 0; ks < 4; ++ks){
    #pragma unroll
    for (int ct = 0; ct < 7; ++ct){
      const uint32_t off = (uint32_t)((ct*16 + lc)*224 + ks*64 + l4*16);
      short8v bF = *(const short8v*)((const char*)ksF + off);
      short8v bL = *(const short8v*)((const char*)ksL + off);
      acc[ct] = __builtin_amdgcn_mfma_f32_16x16x32_bf16(aF[ks], bF, acc[ct], 0, 0, 0);
      acc[ct] = __builtin_amdgcn_mfma_f32_16x16x32_bf16(aL[ks], bL, acc[ct], 0, 0, 0);
    }
  }

  const float sF = 2.f/(1.f + __expf(-fad_gamma[0])) - 1.f;
  const float sL = 2.f/(1.f + __expf(-lfs_gamma[0])) - 1.f;
  unsigned short* attnP = qF + plane;
  unsigned short* alin = ksF;

  __syncthreads();
  #pragma unroll
  for (int r = 0; r < 4; ++r){
    const int i = w*16 + l4*4 + r;
    float v[7];
    #pragma unroll
    for (int ct = 0; ct < 7; ++ct) v[ct] = acc[ct][r];
    float m = fmaxf(fmaxf(fmaxf(v[0],v[1]),fmaxf(v[2],v[3])), fmaxf(fmaxf(v[4],v[5]),v[6]));
    #pragma unroll
    for (int off = 8; off; off >>= 1) m = fmaxf(m, __shfl_xor(m, off, 64));
    float e[7]; float s = 0.f;
    #pragma unroll
    for (int ct = 0; ct < 7; ++ct){ e[ct] = __expf(v[ct] - m); s += e[ct]; }
    #pragma unroll
    for (int off = 8; off; off >>= 1) s += __shfl_xor(s, off, 64);
    const float inv = 1.f / s;
    #pragma unroll
    for (int ct = 0; ct < 7; ++ct)
      alin[i*SS + ct*16 + lc] = f2bf(e[ct] * inv);
  }
  __syncthreads();

  float ls1 = 0.f, lq1 = 0.f, ls2 = 0.f, lq2 = 0.f;
  #pragma unroll
  for (int t = 0; t < 7; ++t){
    const int i4 = tid + t*448;
    ushort4 av = *(const ushort4*)(alin + i4*4);
    *(ushort4*)(attnP + (size_t)i4*4) = av;
    float4 fr = *(const float4*)(fre + plane + (size_t)i4*4);
    float4 rg = *(const float4*)(rgb + plane + (size_t)i4*4);
    const unsigned short* ap = &av.x;
    const float fp[4] = {fr.x, fr.y, fr.z, fr.w};
    const float rp[4] = {rg.x, rg.y, rg.z, rg.w};
    #pragma unroll
    for (int j = 0; j < 4; ++j){
      float a = bf2f(ap[j]);
      float v1 = fp[j] * a * sL;
      float v2 = rp[j] * a * sF;
      ls1 += v1; lq1 += v1*v1; ls2 += v2; lq2 += v2*v2;
    }
  }
  #pragma unroll
  for (int off = 32; off; off >>= 1){
    ls1 += __shfl_xor(ls1, off, 64);
    lq1 += __shfl_xor(lq1, off, 64);
    ls2 += __shfl_xor(ls2, off, 64);
    lq2 += __shfl_xor(lq2, off, 64);
  }
  if (lane == 0){
    atomicAdd(&stats[c],       ls1);
    atomicAdd(&stats[64 + c],  lq1);
    atomicAdd(&stats[128 + c], ls2);
    atomicAdd(&stats[192 + c], lq2);
  }
}

// ---------------- K3: bn1 stats -> affine ----------------
__global__ void k3_affine1(const float* __restrict__ stats,
    const float* __restrict__ fad_cw, const float* __restrict__ fad_bg, const float* __restrict__ fad_bb,
    const float* __restrict__ lfs_cw, const float* __restrict__ lfs_bg, const float* __restrict__ lfs_bb,
    float* __restrict__ AB)
{
  int c = threadIdx.x;
  if (c >= 64) return;
  const float n = 401408.f;
  {
    float m1 = stats[c]/n, v1 = stats[64+c]/n - (stats[c]/n)*(stats[c]/n);
    float cw = fad_cw[c], g = fad_bg[c];
    float rs = rsqrtf(cw*cw*v1 + EPSV);
    AB[c]      = cw*rs*g;
    AB[64 + c] = -cw*m1*rs*g + fad_bb[c];
  }
  {
    float m2 = stats[128+c]/n, v2 = stats[192+c]/n - (stats[128+c]/n)*(stats[128+c]/n);
    float cw = lfs_cw[c], g = lfs_bg[c];
    float rs = rsqrtf(cw*cw*v2 + EPSV);
    AB[128 + c] = cw*rs*g;
    AB[192 + c] = -cw*m2*rs*g + lfs_bb[c];
  }
}

// ---------------- K4: y in-flight + pooling + per-plane stats ----------------
__global__ __launch_bounds__(512) void k4_fuse(
    const unsigned short* __restrict__ attn,
    const float* __restrict__ rgb, const float* __restrict__ fre,
    const float* __restrict__ AB1,
    const float* __restrict__ fad_gamma, const float* __restrict__ lfs_gamma,
    float* __restrict__ avgstat, float* __restrict__ maxstat,
    float4* __restrict__ planeStats)
{
  const int bc = blockIdx.x, b = bc >> 6, c = bc & 63;
  const size_t plane = (size_t)bc * PP;
  __shared__ unsigned short ys[2][112][113];
  __shared__ float redA[8][4];
  __shared__ float redS[8], redM[8];
  const int tid = threadIdx.x, lane = tid & 63, w = tid >> 6;
  const float sF = 2.f/(1.f + __expf(-fad_gamma[0])) - 1.f;
  const float sL = 2.f/(1.f + __expf(-lfs_gamma[0])) - 1.f;
  const float A1 = AB1[c], B1 = AB1[64+c], A2 = AB1[128+c], B2 = AB1[192+c];
  float s0 = 0.f, q0 = 0.f, s1 = 0.f, q1 = 0.f;

  for (int i4 = tid; i4 < 3136; i4 += 512){
    ushort4 av = *(const ushort4*)(attn + plane + (size_t)i4*4);
    float4 rg = *(const float4*)(rgb + plane + (size_t)i4*4);
    float4 fr = *(const float4*)(fre + plane + (size_t)i4*4);
    float aa[4] = {bf2f(av.x), bf2f(av.y), bf2f(av.z), bf2f(av.w)};
    float rr[4] = {rg.x, rg.y, rg.z, rg.w};
    float ff[4] = {fr.x, fr.y, fr.z, fr.w};
    int r = i4 / 28, c0 = (i4 % 28) * 4;
    float y0[4], y1[4];
    #pragma unroll
    for (int j = 0; j < 4; ++j){
      float t1 = ff[j]*aa[j]*sL;
      float t2 = rr[j]*aa[j]*sF;
      y0[j] = rr[j] + A1*t1 + B1;
      y1[j] = ff[j] + A2*t2 + B2;
      s0 += y0[j]; q0 += y0[j]*y0[j];
      s1 += y1[j]; q1 += y1[j]*y1[j];
    }
    *(ushort4*)(&ys[0][r][c0]) = f2bf4(y0[0], y0[1], y0[2], y0[3]);
    *(ushort4*)(&ys[1][r][c0]) = f2bf4(y1[0], y1[1], y1[2], y1[3]);
  }
  #pragma unroll
  for (int off = 32; off; off >>= 1){
    s0 += __shfl_xor(s0, off, 64); q0 += __shfl_xor(q0, off, 64);
    s1 += __shfl_xor(s1, off, 64); q1 += __shfl_xor(q1, off, 64);
  }
  if (lane == 0){ redA[w][0] = s0; redA[w][1] = q0; redA[w][2] = s1; redA[w][3] = q1; }
  __syncthreads();
  if (tid == 0){
    float a0=0,a1=0,a2=0,a3=0;
    for (int i = 0; i < 8; ++i){ a0+=redA[i][0]; a1+=redA[i][1]; a2+=redA[i][2]; a3+=redA[i][3]; }
    float4 ps = {a0,a1,a2,a3};
    planeStats[bc] = ps;
  }
  __syncthreads();

  const int kk[3] = {3,5,7};
  const int gg[3] = {37,22,16};
  for (int pl = 0; pl < 2; ++pl){
    const int cc = pl*64 + c;
    for (int ki = 0; ki < 3; ++ki){
      const int k = kk[ki], g = gg[ki];
      float sumAll = 0.f, mx = -3.0e38f;
      for (int win = tid; win < g*g; win += 512){
        int wy = win / g, wx = win % g;
        float s = 0.f;
        for (int dy = 0; dy < k; ++dy)
          for (int dx = 0; dx < k; ++dx)
            s += bf2f(ys[pl][wy*k+dy][wx*k+dx]);
        sumAll += s; mx = fmaxf(mx, s);
      }
      #pragma unroll
      for (int off = 32; off; off >>= 1){
        sumAll += __shfl_xor(sumAll, off, 64);
        mx = fmaxf(mx, __shfl_xor(mx, off, 64));
      }
      if (lane == 0){ redS[w] = sumAll; redM[w] = mx; }
      __syncthreads();
      if (tid == 0){
        float st = 0.f, mt = -3.0e38f;
        for (int i = 0; i < 8; ++i){ st += redS[i]; mt = fmaxf(mt, redM[i]); }
        int idx = (b*128 + cc)*3 + ki;
        avgstat[idx] = st / (float)(k*k*g*g);
        maxstat[idx] = mt / (float)(k*k);
      }
      __syncthreads();
    }
  }
}

// ---------------- K6: channel-attention MLP ----------------
__global__ void k6_mlp(const float* __restrict__ avgstat, const float* __restrict__ maxstat,
    const float* __restrict__ lin1, const float* __restrict__ lin2,
    const float* __restrict__ w1, const float* __restrict__ w2,
    float* __restrict__ ca)
{
  const int b = blockIdx.x, tid = threadIdx.x; // 128 threads
  __shared__ float sa[128], sm[128], hA[16], hM[16];
  int idx = (b*128 + tid)*3;
  sa[tid] = avgstat[idx]*lin1[0] + avgstat[idx+1]*lin1[1] + avgstat[idx+2]*lin1[2];
  sm[tid] = maxstat[idx]*lin2[0] + maxstat[idx+1]*lin2[1] + maxstat[idx+2]*lin2[2];
  __syncthreads();
  if (tid < 16){
    float ha = 0.f, hm = 0.f;
    for (int c2 = 0; c2 < 128; ++c2){
      ha += w1[tid*128 + c2]*sa[c2];
      hm += w1[tid*128 + c2]*sm[c2];
    }
    hA[tid] = fmaxf(ha, 0.f); hM[tid] = fmaxf(hm, 0.f);
  }
  __syncthreads();
  float o = 0.f;
  for (int r = 0; r < 16; ++r) o += w2[tid*16 + r]*(hA[r] + hM[r]);
  ca[b*128 + tid] = 1.f/(1.f + __expf(-o));
}

// ---------------- K8: final bn affine from per-plane stats + ca ----------------
__global__ void k8_affineF(const float4* __restrict__ planeStats, const float* __restrict__ ca,
    const float* __restrict__ rgb_cw, const float* __restrict__ rgb_bg, const float* __restrict__ rgb_bb,
    const float* __restrict__ fre_cw, const float* __restrict__ fre_bg, const float* __restrict__ fre_bb,
    float* __restrict__ ABF)
{
  int t = threadIdx.x;
  if (t >= 128) return;
  int z = t >> 6, c = t & 63;
  float S = 0.f, Q = 0.f;
  for (int b = 0; b < 32; ++b){
    float4 ps = planeStats[b*64 + c];
    float sc = ca[b*128 + t];
    float sp = z ? ps.z : ps.x;
    float qp = z ? ps.w : ps.y;
    S += sc*sp; Q += sc*sc*qp;
  }
  const float n = 401408.f;
  float m = S/n, v = Q/n - m*m;
  float cw = z ? fre_cw[c] : rgb_cw[c];
  float g  = z ? fre_bg[c] : rgb_bg[c];
  float bb = z ? fre_bb[c] : rgb_bb[c];
  float rs = rsqrtf(cw*cw*v + EPSV);
  ABF[z*128 + c]      = cw*rs*g;
  ABF[z*128 + 64 + c] = -cw*m*rs*g + bb;
}

// ---------------- K9: recompute y from attn, write both outputs ----------------
__global__ __launch_bounds__(256) void k9_out(
    const unsigned short* __restrict__ attn,
    const float* __restrict__ rgb, const float* __restrict__ fre,
    const float* __restrict__ AB1,
    const float* __restrict__ fad_gamma, const float* __restrict__ lfs_gamma,
    const float* __restrict__ ca, const float* __restrict__ ABF,
    float* __restrict__ out)
{
  const int c = blockIdx.x, b = blockIdx.y;
  const size_t plane = ((size_t)b*64 + c)*PP;
  const float sF = 2.f/(1.f + __expf(-fad_gamma[0])) - 1.f;
  const float sL = 2.f/(1.f + __expf(-lfs_gamma[0])) - 1.f;
  const float A1 = AB1[c], B1 = AB1[64+c], A2 = AB1[128+c], B2 = AB1[192+c];
  const float r_c = ca[b*128 + c], f_c = ca[b*128 + 64 + c];
  const float mul0 = 1.f + ABF[c]*r_c,        add0 = ABF[64 + c];
  const float mul1 = 1.f + ABF[128 + c]*f_c,  add1 = ABF[192 + c];
  float* o0 = out + plane;
  float* o1 = out + NE + plane;
  for (int i4 = threadIdx.x; i4 < 3136; i4 += 256){
    ushort4 av = *(const ushort4*)(attn + plane + (size_t)i4*4);
    float4 rg = *(const float4*)(rgb + plane + (size_t)i4*4);
    float4 fr = *(const float4*)(fre + plane + (size_t)i4*4);
    float aa[4] = {bf2f(av.x), bf2f(av.y), bf2f(av.z), bf2f(av.w)};
    float rr[4] = {rg.x, rg.y, rg.z, rg.w};
    float ff[4] = {fr.x, fr.y, fr.z, fr.w};
    float4 v0, v1;
    float* p0 = &v0.x; float* p1 = &v1.x;
    #pragma unroll
    for (int j = 0; j < 4; ++j){
      float t1 = ff[j]*aa[j]*sL;
      float t2 = rr[j]*aa[j]*sF;
      float y0 = rr[j] + A1*t1 + B1;
      float y1 = ff[j] + A2*t2 + B2;
      p0[j] = y0*mul0 + add0;
      p1[j] = y1*mul1 + add1;
    }
    *(float4*)(&o0[(size_t)i4*4]) = v0;
    *(float4*)(&o1[(size_t)i4*4]) = v1;
  }
}

extern "C" void kernel_launch(void* const* d_in, const int* in_sizes, int n_in,
                              void* d_out, int out_size, void* d_ws, size_t ws_size,
                              hipStream_t stream)
{
  (void)in_sizes; (void)n_in; (void)out_size; (void)ws_size;
  const float* rgb      = (const float*)d_in[0];
  const float* fre      = (const float*)d_in[1];
  const float* wq_fad   = (const float*)d_in[2];
  const float* bq_fad   = (const float*)d_in[3];
  const float* wq_lfs   = (const float*)d_in[4];
  const float* bq_lfs   = (const float*)d_in[5];
  const float* wk_fad   = (const float*)d_in[6];
  const float* bk_fad   = (const float*)d_in[7];
  const float* wk_lfs   = (const float*)d_in[8];
  const float* bk_lfs   = (const float*)d_in[9];
  const float* fad_gamma= (const float*)d_in[10];
  const float* lfs_gamma= (const float*)d_in[11];
  const float* fad_cw   = (const float*)d_in[12];
  const float* fad_bg   = (const float*)d_in[14];
  const float* fad_bb   = (const float*)d_in[15];
  const float* lfs_cw   = (const float*)d_in[16];
  const float* lfs_bg   = (const float*)d_in[18];
  const float* lfs_bb   = (const float*)d_in[19];
  const float* lin1_w   = (const float*)d_in[20];
  const float* lin2_w   = (const float*)d_in[21];
  const float* mlp_w1   = (const float*)d_in[22];
  const float* mlp_w2   = (const float*)d_in[23];
  const float* rgb_cw   = (const float*)d_in[24];
  const float* rgb_bg   = (const float*)d_in[26];
  const float* rgb_bb   = (const float*)d_in[27];
  const float* fre_cw   = (const float*)d_in[28];
  const float* fre_bg   = (const float*)d_in[30];
  const float* fre_bb   = (const float*)d_in[31];

  char* ws = (char*)d_ws;
  unsigned short* qF = (unsigned short*)(ws);          // becomes attn after k2
  unsigned short* qL = (unsigned short*)(ws + 2*NE);
  unsigned short* kF = (unsigned short*)(ws + 4*NE);
  unsigned short* kL = (unsigned short*)(ws + 6*NE);
  float* sbase = (float*)(ws + 8*NE);
  float* stats      = sbase;               // [0..255]   bn1 atomics (memset)
  float* AB1        = sbase + 256;
  float* avgstat    = sbase + 512;
  float* maxstat    = sbase + 12800;
  float* ca         = sbase + 25088;
  float* ABF        = sbase + 29184;
  float4* planeStats= (float4*)(sbase + 29440);

  hipMemsetAsync(stats, 0, 256*sizeof(float), stream);

  k1_conv<<<dim3(49,32,2), dim3(256), 0, stream>>>(rgb, fre,
      wq_fad, bq_fad, wk_fad, bk_fad, wq_lfs, bq_lfs, wk_lfs, bk_lfs,
      qF, kF, qL, kL);
  k2_attn<<<dim3(2048), dim3(448), 0, stream>>>(qF, qL, kF, kL,
      rgb, fre, fad_gamma, lfs_gamma, stats);
  k3_affine1<<<dim3(1), dim3(64), 0, stream>>>(stats,
      fad_cw, fad_bg, fad_bb, lfs_cw, lfs_bg, lfs_bb, AB1);
  k4_fuse<<<dim3(2048), dim3(512), 0, stream>>>((const unsigned short*)qF,
      rgb, fre, AB1, fad_gamma, lfs_gamma, avgstat, maxstat, planeStats);
  k6_mlp<<<dim3(32), dim3(128), 0, stream>>>(avgstat, maxstat,
      lin1_w, lin2_w, mlp_w1, mlp_w2, ca);
  k8_affineF<<<dim3(1), dim3(128), 0, stream>>>(planeStats, ca,
      rgb_cw, rgb_bg, rgb_bb, fre_cw, fre_bg, fre_bb, ABF);
  k9_out<<<dim3(64,32), dim3(256), 0, stream>>>((const unsigned short*)qF,
      rgb, fre, AB1, fad_gamma, lfs_gamma, ca, ABF, (float*)d_out);
}